// Round 1
// baseline (163.079 us; speedup 1.0000x reference)
//
#include <hip/hip_runtime.h>

typedef unsigned short u16;
typedef short v8s __attribute__((ext_vector_type(8)));
typedef float v4f __attribute__((ext_vector_type(4)));

#define S_TOK 4096
#define MDIM  1024
#define NEXP  8
#define CAPN  1024

// ---------- helpers ----------
__device__ __forceinline__ u16 f2bf(float f) {
  unsigned int u = __float_as_uint(f);
  u += 0x7FFFu + ((u >> 16) & 1u);   // round-to-nearest-even
  return (u16)(u >> 16);
}

__device__ __forceinline__ void gll16(const void* g, void* l) {
  __builtin_amdgcn_global_load_lds(
      (const __attribute__((address_space(1))) void*)g,
      (__attribute__((address_space(3))) void*)l, 16, 0, 0);
}

// ---------- 1. init: slot_token=-1, zero row, gate sums ----------
__global__ __launch_bounds__(256) void init_kernel(int* slot_token, u16* zrow, float* gsum) {
  int gid = blockIdx.x * 256 + threadIdx.x;
  if (gid < NEXP * CAPN) slot_token[gid] = -1;
  if (gid < MDIM) zrow[gid] = 0;
  if (gid < NEXP) gsum[gid] = 0.f;
}

// ---------- 2. transpose+convert W: [e][m][n] f32 -> [e][n][m] bf16 ----------
__global__ __launch_bounds__(256) void transw_kernel(const float* __restrict__ w,
                                                     u16* __restrict__ wT) {
  int b  = blockIdx.x;          // e*256 + mt*16 + nt
  int e  = b >> 8;
  int mt = (b >> 4) & 15;
  int nt = b & 15;
  __shared__ float tile[64][65];
  const float* src = w + (size_t)e * MDIM * MDIM;
  u16* dst = wT + (size_t)e * MDIM * MDIM;
  int tid = threadIdx.x;
#pragma unroll
  for (int i = 0; i < 16; i++) {
    int idx = tid + i * 256;           // 0..4095
    int r = idx >> 6, c = idx & 63;
    tile[r][c] = src[(size_t)(mt * 64 + r) * MDIM + nt * 64 + c];
  }
  __syncthreads();
#pragma unroll
  for (int i = 0; i < 16; i++) {
    int idx = tid + i * 256;
    int r = idx >> 6, c = idx & 63;    // r = local n, c = local m
    dst[(size_t)(nt * 64 + r) * MDIM + mt * 64 + c] = f2bf(tile[c][r]);
  }
}

// ---------- 3. gate: logits(f32), softmax, top1/top2; fused x->bf16 ----------
__global__ __launch_bounds__(256) void gate_kernel(const float* __restrict__ x,
                                                   const float* __restrict__ wg,
                                                   u16* __restrict__ xbf,
                                                   int4* __restrict__ grec,
                                                   float* __restrict__ gsum) {
  __shared__ float wls[NEXP * MDIM];   // transposed: wls[e*1024 + m]
  __shared__ float gsh[4][NEXP];
  int tid = threadIdx.x;
  for (int i = tid; i < NEXP * MDIM; i += 256) {
    int m = i >> 3, e = i & 7;
    wls[e * MDIM + m] = wg[i];
  }
  __syncthreads();
  int wave = tid >> 6, lane = tid & 63;
  int s = blockIdx.x * 4 + wave;
  const float* xr = x + (size_t)s * MDIM;
  u16* xw = xbf + (size_t)s * MDIM;
  float acc[NEXP];
#pragma unroll
  for (int e = 0; e < NEXP; e++) acc[e] = 0.f;
#pragma unroll
  for (int j = 0; j < 16; j++) {
    int m = j * 64 + lane;
    float xv = xr[m];
    xw[m] = f2bf(xv);
#pragma unroll
    for (int e = 0; e < NEXP; e++) acc[e] = fmaf(xv, wls[e * MDIM + m], acc[e]);
  }
#pragma unroll
  for (int off = 32; off > 0; off >>= 1)
#pragma unroll
    for (int e = 0; e < NEXP; e++) acc[e] += __shfl_xor(acc[e], off, 64);

  if (lane == 0) {
    float mx = acc[0];
#pragma unroll
    for (int e = 1; e < NEXP; e++) mx = fmaxf(mx, acc[e]);
    float ex[NEXP], sum = 0.f;
#pragma unroll
    for (int e = 0; e < NEXP; e++) { ex[e] = expf(acc[e] - mx); sum += ex[e]; }
    float inv = 1.f / sum;
    int e1 = 0; float b1 = acc[0];
#pragma unroll
    for (int e = 1; e < NEXP; e++) if (acc[e] > b1) { b1 = acc[e]; e1 = e; }
    int e2 = -1; float b2 = -3.4e38f;
#pragma unroll
    for (int e = 0; e < NEXP; e++) if (e != e1 && acc[e] > b2) { b2 = acc[e]; e2 = e; }
    grec[s] = make_int4(e1, e2, __float_as_int(ex[e1] * inv), __float_as_int(ex[e2] * inv));
#pragma unroll
    for (int e = 0; e < NEXP; e++) gsh[wave][e] = ex[e] * inv;
  }
  __syncthreads();
  if (tid < NEXP)
    atomicAdd(&gsum[tid], gsh[0][tid] + gsh[1][tid] + gsh[2][tid] + gsh[3][tid]);
}

// ---------- 4. scan: per-expert cumsum, capacity drop, slots, l_aux ----------
__global__ __launch_bounds__(1024) void scan_kernel(const int4* __restrict__ grec,
                                                    int4* __restrict__ trec,
                                                    int* __restrict__ slot_token,
                                                    const float* __restrict__ gsum,
                                                    float* __restrict__ out) {
  __shared__ unsigned long long scanA[1024], scanB[1024];
  int t = threadIdx.x;
  int e1[4], e2[4];
  float g1[4], g2[4];
#pragma unroll
  for (int i = 0; i < 4; i++) {
    int4 r = grec[t * 4 + i];
    e1[i] = r.x; e2[i] = r.y;
    g1[i] = __int_as_float(r.z); g2[i] = __int_as_float(r.w);
  }
  // ---- scan of mask1 (packed 8x16-bit across two u64) ----
  unsigned long long a0 = 0, b0 = 0;
#pragma unroll
  for (int i = 0; i < 4; i++) {
    if (e1[i] < 4) a0 += 1ULL << (e1[i] * 16); else b0 += 1ULL << ((e1[i] - 4) * 16);
  }
  scanA[t] = a0; scanB[t] = b0;
  __syncthreads();
  for (int off = 1; off < 1024; off <<= 1) {
    unsigned long long pa = 0, pb = 0;
    if (t >= off) { pa = scanA[t - off]; pb = scanB[t - off]; }
    __syncthreads();
    if (t >= off) { scanA[t] += pa; scanB[t] += pb; }
    __syncthreads();
  }
  unsigned long long ea = scanA[t] - a0, eb2 = scanB[t] - b0;   // exclusive
  unsigned long long ta = scanA[1023], tb = scanB[1023];        // totals
  int base[NEXP], cnt1[NEXP];
#pragma unroll
  for (int e = 0; e < 4; e++) {
    base[e]     = (int)((ea  >> (e * 16)) & 0xFFFF);
    base[4 + e] = (int)((eb2 >> (e * 16)) & 0xFFFF);
    cnt1[e]     = (int)((ta  >> (e * 16)) & 0xFFFF);
    cnt1[4 + e] = (int)((tb  >> (e * 16)) & 0xFFFF);
  }
  int loc1[4];
#pragma unroll
  for (int i = 0; i < 4; i++) {
    int l = 0;
#pragma unroll
    for (int q = 0; q < NEXP; q++) if (q == e1[i]) { l = base[q]; base[q] = l + 1; }
    loc1[i] = l;
  }
  __syncthreads();   // everyone done reading scanA/B before reuse
  // ---- scan of mask2 ----
  a0 = 0; b0 = 0;
#pragma unroll
  for (int i = 0; i < 4; i++) {
    if (e2[i] < 4) a0 += 1ULL << (e2[i] * 16); else b0 += 1ULL << ((e2[i] - 4) * 16);
  }
  scanA[t] = a0; scanB[t] = b0;
  __syncthreads();
  for (int off = 1; off < 1024; off <<= 1) {
    unsigned long long pa = 0, pb = 0;
    if (t >= off) { pa = scanA[t - off]; pb = scanB[t - off]; }
    __syncthreads();
    if (t >= off) { scanA[t] += pa; scanB[t] += pb; }
    __syncthreads();
  }
  ea = scanA[t] - a0; eb2 = scanB[t] - b0;
#pragma unroll
  for (int e = 0; e < 4; e++) {
    base[e]     = (int)((ea  >> (e * 16)) & 0xFFFF);
    base[4 + e] = (int)((eb2 >> (e * 16)) & 0xFFFF);
  }
#pragma unroll
  for (int i = 0; i < 4; i++) {
    int s = t * 4 + i;
    int l2 = 0;
#pragma unroll
    for (int q = 0; q < NEXP; q++) if (q == e2[i]) { l2 = base[q]; base[q] = l2 + 1; }
    int loc2 = l2 + cnt1[e2[i]];
    bool k1 = loc1[i] < CAPN;
    bool k2 = loc2 < CAPN;
    float g1s = k1 ? g1[i] : 0.f;
    float g2s = k2 ? g2[i] : 0.f;
    float denom = fmaxf(g1s + g2s, 1.1920929e-7f);
    float gn1 = g1s / denom, gn2 = g2s / denom;
    int slot1 = k1 ? e1[i] * CAPN + loc1[i] : -1;
    int slot2 = k2 ? e2[i] * CAPN + loc2 : -1;
    trec[s] = make_int4(slot1, slot2, __float_as_int(gn1), __float_as_int(gn2));
    if (k1) slot_token[slot1] = s;
    if (k2) slot_token[slot2] = s;
  }
  if (t == 0) {
    float acc = 0.f;
#pragma unroll
    for (int e = 0; e < NEXP; e++) acc += gsum[e] * (float)cnt1[e];
    out[(size_t)S_TOK * MDIM] = 8.f * acc / (4096.f * 4096.f);
  }
}

// ---------- 5. expert GEMM: gathered A (bf16) x W^T rows, MFMA 16x16x32 ----------
__global__ __launch_bounds__(256, 2) void expert_gemm(const u16* __restrict__ xbf,
                                                      const u16* __restrict__ wT,
                                                      const int* __restrict__ slot_token,
                                                      const u16* __restrict__ zrow,
                                                      float* __restrict__ eout) {
  __shared__ __align__(16) u16 As[128 * 64];
  __shared__ __align__(16) u16 Bs[128 * 64];
  const int tid  = threadIdx.x;
  const int e    = blockIdx.x >> 6;
  const int tile = blockIdx.x & 63;
  const int tm   = (tile >> 3) << 7;
  const int tn   = (tile & 7) << 7;
  const int lane = tid & 63;
  const int wave = tid >> 6;
  const int wr = wave >> 1, wc = wave & 1;

  const u16* srcA[4];
  const u16* srcB[4];
#pragma unroll
  for (int it = 0; it < 4; ++it) {
    int off = tid * 16 + it * 4096;    // byte offset within 16 KB tile
    int row = off >> 7;                // 0..127
    int kb  = off & 127;               // byte offset in the 128B row
    int st  = slot_token[e * CAPN + tm + row];
    srcA[it] = (st >= 0 ? xbf + (size_t)st * MDIM : zrow) + (kb >> 1);
    srcB[it] = wT + (size_t)e * MDIM * MDIM + (size_t)(tn + row) * MDIM + (kb >> 1);
  }
  char* ldsA = (char*)As;
  char* ldsB = (char*)Bs;

  v4f acc[4][4];
#pragma unroll
  for (int i = 0; i < 4; i++)
#pragma unroll
    for (int j = 0; j < 4; j++) acc[i][j] = (v4f){0.f, 0.f, 0.f, 0.f};

  for (int k0 = 0; k0 < MDIM; k0 += 64) {
    __syncthreads();
#pragma unroll
    for (int it = 0; it < 4; ++it)
      gll16(srcA[it] + k0, ldsA + tid * 16 + it * 4096);
#pragma unroll
    for (int it = 0; it < 4; ++it)
      gll16(srcB[it] + k0, ldsB + tid * 16 + it * 4096);
    __syncthreads();

    const v8s* Ap = (const v8s*)As;
    const v8s* Bp = (const v8s*)Bs;
#pragma unroll
    for (int ks = 0; ks < 2; ++ks) {
      v8s af[4], bf[4];
#pragma unroll
      for (int i = 0; i < 4; i++)
        af[i] = Ap[(wr * 64 + i * 16 + (lane & 15)) * 8 + ks * 4 + (lane >> 4)];
#pragma unroll
      for (int j = 0; j < 4; j++)
        bf[j] = Bp[(wc * 64 + j * 16 + (lane & 15)) * 8 + ks * 4 + (lane >> 4)];
#pragma unroll
      for (int i = 0; i < 4; i++)
#pragma unroll
        for (int j = 0; j < 4; j++)
          acc[i][j] = __builtin_amdgcn_mfma_f32_16x16x32_bf16(af[i], bf[j], acc[i][j], 0, 0, 0);
    }
  }

  float* outp = eout + (size_t)e * CAPN * MDIM;
#pragma unroll
  for (int i = 0; i < 4; i++) {
#pragma unroll
    for (int r = 0; r < 4; r++) {
      int row = tm + wr * 64 + i * 16 + (lane >> 4) * 4 + r;
#pragma unroll
      for (int j = 0; j < 4; j++) {
        int col = tn + wc * 64 + j * 16 + (lane & 15);
        outp[(size_t)row * MDIM + col] = acc[i][j][r];
      }
    }
  }
}

// ---------- 6. combine: y = g1*(out1+b1) + g2*(out2+b2) ----------
__global__ __launch_bounds__(256) void combine_kernel(const float* __restrict__ eout,
                                                      const int4* __restrict__ trec,
                                                      const float* __restrict__ bias,
                                                      float* __restrict__ out) {
  int s = blockIdx.x;
  int tid = threadIdx.x;
  int4 r = trec[s];
  float g1 = __int_as_float(r.z), g2 = __int_as_float(r.w);
  const float4* e4 = (const float4*)eout;
  const float4* b4 = (const float4*)bias;
  float yx = 0.f, yy = 0.f, yz = 0.f, yw = 0.f;
  if (r.x >= 0) {
    float4 o = e4[(size_t)r.x * 256 + tid];
    float4 b = b4[(size_t)(r.x >> 10) * 256 + tid];
    yx += g1 * (o.x + b.x); yy += g1 * (o.y + b.y);
    yz += g1 * (o.z + b.z); yw += g1 * (o.w + b.w);
  }
  if (r.y >= 0) {
    float4 o = e4[(size_t)r.y * 256 + tid];
    float4 b = b4[(size_t)(r.y >> 10) * 256 + tid];
    yx += g2 * (o.x + b.x); yy += g2 * (o.y + b.y);
    yz += g2 * (o.z + b.z); yw += g2 * (o.w + b.w);
  }
  float4 res; res.x = yx; res.y = yy; res.z = yz; res.w = yw;
  ((float4*)out)[(size_t)s * 256 + tid] = res;
}

// ---------- launcher ----------
extern "C" void kernel_launch(void* const* d_in, const int* in_sizes, int n_in,
                              void* d_out, int out_size, void* d_ws, size_t ws_size,
                              hipStream_t stream) {
  (void)in_sizes; (void)n_in; (void)out_size; (void)ws_size;
  const float* x  = (const float*)d_in[0];
  const float* wg = (const float*)d_in[1];
  const float* ew = (const float*)d_in[2];
  const float* eb = (const float*)d_in[3];
  float* out = (float*)d_out;

  char* ws = (char*)d_ws;
  // ws layout (bytes):
  //   [0,        8388608)  x bf16         [S=4096][M=1024]
  //   [8388608, 25165824)  W^T bf16       [E=8][N=1024][M=1024]
  //   [25165824,58720256)  expert_out f32 [E=8][C=1024][N=1024]
  //   [58720256,58722304)  zero row bf16  [1024]
  //   [58722304,58787840)  gate recs int4 [4096]
  //   [58787840,58853376)  token recs int4[4096]
  //   [58853376,58886144)  slot_token int [8192]
  //   [58886144,58886176)  gate sums f32  [8]
  u16*   xbf  = (u16*)(ws + 0);
  u16*   wT   = (u16*)(ws + 8388608);
  float* eout = (float*)(ws + 25165824);
  u16*   zrow = (u16*)(ws + 58720256);
  int4*  grec = (int4*)(ws + 58722304);
  int4*  trec = (int4*)(ws + 58787840);
  int*   slot = (int*)(ws + 58853376);
  float* gsum = (float*)(ws + 58886144);

  init_kernel<<<32, 256, 0, stream>>>(slot, zrow, gsum);
  transw_kernel<<<2048, 256, 0, stream>>>(ew, wT);
  gate_kernel<<<1024, 256, 0, stream>>>(x, wg, xbf, grec, gsum);
  scan_kernel<<<1, 1024, 0, stream>>>(grec, trec, slot, gsum, out);
  expert_gemm<<<512, 256, 0, stream>>>(xbf, wT, slot, zrow, eout);
  combine_kernel<<<4096, 256, 0, stream>>>(eout, trec, eb, out);
}

// Round 2
// 147.821 us; speedup vs baseline: 1.1032x; 1.1032x over previous
//
#include <hip/hip_runtime.h>

typedef unsigned short u16;
typedef unsigned int u32;
typedef unsigned long long u64;
typedef short v8s __attribute__((ext_vector_type(8)));
typedef float v4f __attribute__((ext_vector_type(4)));

#define S_TOK 4096
#define MDIM  1024
#define NEXP  8
#define CAPN  1024

// ---------- helpers ----------
__device__ __forceinline__ u16 f2bf(float f) {
  u32 u = __float_as_uint(f);
  u += 0x7FFFu + ((u >> 16) & 1u);   // round-to-nearest-even
  return (u16)(u >> 16);
}
__device__ __forceinline__ float bf2f(u16 h) {
  return __uint_as_float(((u32)h) << 16);
}
__device__ __forceinline__ void gll16(const void* g, void* l) {
  __builtin_amdgcn_global_load_lds(
      (const __attribute__((address_space(1))) void*)g,
      (__attribute__((address_space(3))) void*)l, 16, 0, 0);
}

// ---------- 1. transpose+convert W: [e][m][n] f32 -> [e][n][m] bf16 ----------
__global__ __launch_bounds__(256) void transw_kernel(const float* __restrict__ w,
                                                     u16* __restrict__ wT) {
  int b  = blockIdx.x;          // e*256 + mt*16 + nt
  int e  = b >> 8;
  int mt = (b >> 4) & 15;
  int nt = b & 15;
  __shared__ float tile[64][65];
  const float* src = w + (size_t)e * MDIM * MDIM;
  u16* dst = wT + (size_t)e * MDIM * MDIM;
  int tid = threadIdx.x;
#pragma unroll
  for (int i = 0; i < 16; i++) {
    int idx = tid + i * 256;           // 0..4095
    int r = idx >> 6, c = idx & 63;
    tile[r][c] = src[(size_t)(mt * 64 + r) * MDIM + nt * 64 + c];
  }
  __syncthreads();
#pragma unroll
  for (int i = 0; i < 16; i++) {
    int idx = tid + i * 256;
    int r = idx >> 6, c = idx & 63;    // r = local n, c = local m
    dst[(size_t)(nt * 64 + r) * MDIM + mt * 64 + c] = f2bf(tile[c][r]);
  }
}

// ---------- 2. gate: fp32 logits, softmax, top1/top2; fused x->bf16 ----------
__global__ __launch_bounds__(256) void gate_kernel(const float* __restrict__ x,
                                                   const float* __restrict__ wg,
                                                   u16* __restrict__ xbf,
                                                   int4* __restrict__ grec,
                                                   float* __restrict__ gpart) {
  __shared__ float wls[NEXP * MDIM];   // transposed: wls[e*1024 + m]
  __shared__ float gsh[4][NEXP];
  int tid = threadIdx.x;
  for (int i = tid; i < NEXP * MDIM; i += 256) {
    int m = i >> 3, e = i & 7;
    wls[e * MDIM + m] = wg[i];
  }
  __syncthreads();
  int wave = tid >> 6, lane = tid & 63;
  int s = blockIdx.x * 4 + wave;
  const float* xr = x + (size_t)s * MDIM;
  u16* xw = xbf + (size_t)s * MDIM;
  float acc[NEXP];
#pragma unroll
  for (int e = 0; e < NEXP; e++) acc[e] = 0.f;
#pragma unroll
  for (int j = 0; j < 16; j++) {
    int m = j * 64 + lane;
    float xv = xr[m];
    xw[m] = f2bf(xv);
#pragma unroll
    for (int e = 0; e < NEXP; e++) acc[e] = fmaf(xv, wls[e * MDIM + m], acc[e]);
  }
#pragma unroll
  for (int off = 32; off > 0; off >>= 1)
#pragma unroll
    for (int e = 0; e < NEXP; e++) acc[e] += __shfl_xor(acc[e], off, 64);

  if (lane == 0) {
    float mx = acc[0];
#pragma unroll
    for (int e = 1; e < NEXP; e++) mx = fmaxf(mx, acc[e]);
    float ex[NEXP], sum = 0.f;
#pragma unroll
    for (int e = 0; e < NEXP; e++) { ex[e] = expf(acc[e] - mx); sum += ex[e]; }
    float inv = 1.f / sum;
    int e1 = 0; float b1 = acc[0];
#pragma unroll
    for (int e = 1; e < NEXP; e++) if (acc[e] > b1) { b1 = acc[e]; e1 = e; }
    int e2 = -1; float b2 = -3.4e38f;
#pragma unroll
    for (int e = 0; e < NEXP; e++) if (e != e1 && acc[e] > b2) { b2 = acc[e]; e2 = e; }
    grec[s] = make_int4(e1, e2, __float_as_int(ex[e1] * inv), __float_as_int(ex[e2] * inv));
#pragma unroll
    for (int e = 0; e < NEXP; e++) gsh[wave][e] = ex[e] * inv;
  }
  __syncthreads();
  if (tid < NEXP)
    gpart[blockIdx.x * NEXP + tid] = gsh[0][tid] + gsh[1][tid] + gsh[2][tid] + gsh[3][tid];
}

// ---------- 3. scan: wave-shuffle cumsum, capacity drop, slots, init, l_aux ----------
__global__ __launch_bounds__(1024) void scan_kernel(const int4* __restrict__ grec,
                                                    int4* __restrict__ trec,
                                                    int* __restrict__ slot_token,
                                                    const float* __restrict__ gpart,
                                                    u16* __restrict__ zrow,
                                                    float* __restrict__ out) {
  __shared__ u64 wtot[16][4];
  __shared__ float gred[16][NEXP];
  int t = threadIdx.x, lane = t & 63, wave = t >> 6;

  // fused init (single block: __syncthreads orders these vs the scatter below)
#pragma unroll
  for (int i = 0; i < 8; i++) slot_token[t + i * 1024] = -1;
  zrow[t] = 0;

  // reduce per-block gate sums (for l_aux)
  float4 p0 = ((const float4*)gpart)[t * 2];
  float4 p1 = ((const float4*)gpart)[t * 2 + 1];
  float gs[NEXP] = {p0.x, p0.y, p0.z, p0.w, p1.x, p1.y, p1.z, p1.w};
#pragma unroll
  for (int off = 32; off > 0; off >>= 1)
#pragma unroll
    for (int e = 0; e < NEXP; e++) gs[e] += __shfl_xor(gs[e], off, 64);
  if (lane == 0)
#pragma unroll
    for (int e = 0; e < NEXP; e++) gred[wave][e] = gs[e];

  // load 4 tokens' gate records
  int4 r[4];
#pragma unroll
  for (int i = 0; i < 4; i++) r[i] = grec[t * 4 + i];

  // per-thread aggregates: 8 experts x 16-bit counters, mask1 in (a1,b1), mask2 in (a2,b2)
  u64 a1 = 0, b1 = 0, a2 = 0, b2 = 0;
#pragma unroll
  for (int i = 0; i < 4; i++) {
    int x1 = r[i].x, x2 = r[i].y;
    if (x1 < 4) a1 += 1ULL << (x1 * 16); else b1 += 1ULL << ((x1 - 4) * 16);
    if (x2 < 4) a2 += 1ULL << (x2 * 16); else b2 += 1ULL << ((x2 - 4) * 16);
  }
  u64 ia1 = a1, ib1 = b1, ia2 = a2, ib2 = b2;
  // wave-level inclusive scan (6 shuffle steps, all 4 counters at once)
#pragma unroll
  for (int off = 1; off < 64; off <<= 1) {
    u64 s1 = __shfl_up(a1, off, 64), s2 = __shfl_up(b1, off, 64);
    u64 s3 = __shfl_up(a2, off, 64), s4 = __shfl_up(b2, off, 64);
    if (lane >= off) { a1 += s1; b1 += s2; a2 += s3; b2 += s4; }
  }
  if (lane == 63) { wtot[wave][0] = a1; wtot[wave][1] = b1; wtot[wave][2] = a2; wtot[wave][3] = b2; }
  __syncthreads();
  if (t < 16) {
    u64 v0 = wtot[t][0], v1 = wtot[t][1], v2 = wtot[t][2], v3 = wtot[t][3];
#pragma unroll
    for (int off = 1; off < 16; off <<= 1) {
      u64 s0 = __shfl_up(v0, off, 64), s1 = __shfl_up(v1, off, 64);
      u64 s2 = __shfl_up(v2, off, 64), s3 = __shfl_up(v3, off, 64);
      if (t >= off) { v0 += s0; v1 += s1; v2 += s2; v3 += s3; }
    }
    wtot[t][0] = v0; wtot[t][1] = v1; wtot[t][2] = v2; wtot[t][3] = v3;
  }
  __syncthreads();
  u64 o1 = 0, o2 = 0, o3 = 0, o4 = 0;
  if (wave > 0) { o1 = wtot[wave - 1][0]; o2 = wtot[wave - 1][1]; o3 = wtot[wave - 1][2]; o4 = wtot[wave - 1][3]; }
  u64 ea  = a1 + o1 - ia1;   // exclusive prefix, mask1
  u64 eb  = b1 + o2 - ib1;
  u64 ea2 = a2 + o3 - ia2;   // exclusive prefix, mask2
  u64 eb2 = b2 + o4 - ib2;
  u64 ta = wtot[15][0], tb = wtot[15][1];   // mask1 totals

  int base1[NEXP], base2[NEXP], cnt1[NEXP];
#pragma unroll
  for (int e = 0; e < 4; e++) {
    base1[e]     = (int)((ea  >> (e * 16)) & 0xFFFF);
    base1[4 + e] = (int)((eb  >> (e * 16)) & 0xFFFF);
    base2[e]     = (int)((ea2 >> (e * 16)) & 0xFFFF);
    base2[4 + e] = (int)((eb2 >> (e * 16)) & 0xFFFF);
    cnt1[e]      = (int)((ta  >> (e * 16)) & 0xFFFF);
    cnt1[4 + e]  = (int)((tb  >> (e * 16)) & 0xFFFF);
  }
#pragma unroll
  for (int i = 0; i < 4; i++) {
    int s = t * 4 + i;
    int e1 = r[i].x, e2 = r[i].y;
    float g1 = __int_as_float(r[i].z), g2 = __int_as_float(r[i].w);
    int l1 = 0, l2 = 0;
#pragma unroll
    for (int q = 0; q < NEXP; q++) {
      if (q == e1) { l1 = base1[q]; base1[q] = l1 + 1; }
      if (q == e2) { l2 = base2[q]; base2[q] = l2 + 1; }
    }
    int loc2 = l2 + cnt1[e2];
    bool k1 = l1 < CAPN;
    bool k2 = loc2 < CAPN;
    float g1s = k1 ? g1 : 0.f;
    float g2s = k2 ? g2 : 0.f;
    float denom = fmaxf(g1s + g2s, 1.1920929e-7f);
    float gn1 = g1s / denom, gn2 = g2s / denom;
    int slot1 = k1 ? e1 * CAPN + l1 : -1;
    int slot2 = k2 ? e2 * CAPN + loc2 : -1;
    trec[s] = make_int4(slot1, slot2, __float_as_int(gn1), __float_as_int(gn2));
    if (k1) slot_token[slot1] = s;
    if (k2) slot_token[slot2] = s;
  }
  if (t == 0) {
    float acc = 0.f;
#pragma unroll
    for (int e = 0; e < NEXP; e++) {
      float g = 0.f;
      for (int w = 0; w < 16; w++) g += gred[w][e];
      acc += g * (float)cnt1[e];
    }
    out[(size_t)S_TOK * MDIM] = 8.f * acc / (4096.f * 4096.f);
  }
}

// ---------- 4. expert GEMM: gathered A (bf16) x W^T, MFMA 16x16x32, bf16 out + bias ----------
__global__ __launch_bounds__(256, 2) void expert_gemm(const u16* __restrict__ xbf,
                                                      const u16* __restrict__ wT,
                                                      const int* __restrict__ slot_token,
                                                      const u16* __restrict__ zrow,
                                                      const float* __restrict__ bias,
                                                      u16* __restrict__ eoutb) {
  __shared__ __align__(16) u16 As[128 * 64];
  __shared__ __align__(16) u16 Bs[128 * 64];
  const int tid  = threadIdx.x;
  const int e    = blockIdx.x >> 6;
  const int tile = blockIdx.x & 63;
  const int tm   = (tile >> 3) << 7;
  const int tn   = (tile & 7) << 7;
  const int lane = tid & 63;
  const int wave = tid >> 6;
  const int wr = wave >> 1, wc = wave & 1;

  const u16* srcA[4];
  const u16* srcB[4];
#pragma unroll
  for (int it = 0; it < 4; ++it) {
    int off = tid * 16 + it * 4096;    // byte offset within 16 KB tile
    int row = off >> 7;                // 0..127
    int kb  = off & 127;               // byte offset in the 128B row-chunk
    int st  = slot_token[e * CAPN + tm + row];
    srcA[it] = (st >= 0 ? xbf + (size_t)st * MDIM : zrow) + (kb >> 1);
    srcB[it] = wT + (size_t)e * MDIM * MDIM + (size_t)(tn + row) * MDIM + (kb >> 1);
  }
  char* ldsA = (char*)As;
  char* ldsB = (char*)Bs;

  v4f acc[4][4];
#pragma unroll
  for (int i = 0; i < 4; i++)
#pragma unroll
    for (int j = 0; j < 4; j++) acc[i][j] = (v4f){0.f, 0.f, 0.f, 0.f};

  for (int k0 = 0; k0 < MDIM; k0 += 64) {
    __syncthreads();
#pragma unroll
    for (int it = 0; it < 4; ++it)
      gll16(srcA[it] + k0, ldsA + tid * 16 + it * 4096);
#pragma unroll
    for (int it = 0; it < 4; ++it)
      gll16(srcB[it] + k0, ldsB + tid * 16 + it * 4096);
    __syncthreads();

    const v8s* Ap = (const v8s*)As;
    const v8s* Bp = (const v8s*)Bs;
#pragma unroll
    for (int ks = 0; ks < 2; ++ks) {
      v8s af[4], bfr[4];
#pragma unroll
      for (int i = 0; i < 4; i++)
        af[i] = Ap[(wr * 64 + i * 16 + (lane & 15)) * 8 + ks * 4 + (lane >> 4)];
#pragma unroll
      for (int j = 0; j < 4; j++)
        bfr[j] = Bp[(wc * 64 + j * 16 + (lane & 15)) * 8 + ks * 4 + (lane >> 4)];
#pragma unroll
      for (int i = 0; i < 4; i++)
#pragma unroll
        for (int j = 0; j < 4; j++)
          acc[i][j] = __builtin_amdgcn_mfma_f32_16x16x32_bf16(af[i], bfr[j], acc[i][j], 0, 0, 0);
    }
  }

  // epilogue: add bias (reference adds bias inside expert_out), convert to bf16
  const float* bp = bias + (size_t)e * MDIM;
  float bv[4];
#pragma unroll
  for (int j = 0; j < 4; j++) bv[j] = bp[tn + wc * 64 + j * 16 + (lane & 15)];
  u16* outp = eoutb + (size_t)e * CAPN * MDIM;
#pragma unroll
  for (int i = 0; i < 4; i++) {
#pragma unroll
    for (int rr = 0; rr < 4; rr++) {
      int row = tm + wr * 64 + i * 16 + (lane >> 4) * 4 + rr;
#pragma unroll
      for (int j = 0; j < 4; j++) {
        int col = tn + wc * 64 + j * 16 + (lane & 15);
        outp[(size_t)row * MDIM + col] = f2bf(acc[i][j][rr] + bv[j]);
      }
    }
  }
}

// ---------- 5. combine: y = g1*out1 + g2*out2 (bias already folded in) ----------
__global__ __launch_bounds__(256) void combine_kernel(const u16* __restrict__ eoutb,
                                                      const int4* __restrict__ trec,
                                                      float* __restrict__ out) {
  int s = blockIdx.x;
  int tid = threadIdx.x;
  int4 r = trec[s];
  float g1 = __int_as_float(r.z), g2 = __int_as_float(r.w);
  float4 res = make_float4(0.f, 0.f, 0.f, 0.f);
  if (r.x >= 0) {
    ushort4 o = ((const ushort4*)(eoutb + (size_t)r.x * MDIM))[tid];
    res.x += g1 * bf2f(o.x); res.y += g1 * bf2f(o.y);
    res.z += g1 * bf2f(o.z); res.w += g1 * bf2f(o.w);
  }
  if (r.y >= 0) {
    ushort4 o = ((const ushort4*)(eoutb + (size_t)r.y * MDIM))[tid];
    res.x += g2 * bf2f(o.x); res.y += g2 * bf2f(o.y);
    res.z += g2 * bf2f(o.z); res.w += g2 * bf2f(o.w);
  }
  ((float4*)out)[(size_t)s * 256 + tid] = res;
}

// ---------- launcher ----------
extern "C" void kernel_launch(void* const* d_in, const int* in_sizes, int n_in,
                              void* d_out, int out_size, void* d_ws, size_t ws_size,
                              hipStream_t stream) {
  (void)in_sizes; (void)n_in; (void)out_size; (void)ws_size;
  const float* x  = (const float*)d_in[0];
  const float* wg = (const float*)d_in[1];
  const float* ew = (const float*)d_in[2];
  const float* eb = (const float*)d_in[3];
  float* out = (float*)d_out;

  char* ws = (char*)d_ws;
  // ws layout (bytes):
  //   [0,        8388608)  x bf16          [S=4096][M=1024]
  //   [8388608, 25165824)  W^T bf16        [E=8][N=1024][M=1024]
  //   [25165824,41943040)  expert_out bf16 [E=8][C=1024][N=1024]
  //   [41943040,41945088)  zero row bf16   [1024]
  //   [41945088,42010624)  gate recs int4  [4096]
  //   [42010624,42076160)  token recs int4 [4096]
  //   [42076160,42108928)  slot_token int  [8192]
  //   [42108928,42141696)  gate partials   [1024][8] f32
  u16*   xbf   = (u16*)(ws + 0);
  u16*   wT    = (u16*)(ws + 8388608);
  u16*   eoutb = (u16*)(ws + 25165824);
  u16*   zrow  = (u16*)(ws + 41943040);
  int4*  grec  = (int4*)(ws + 41945088);
  int4*  trec  = (int4*)(ws + 42010624);
  int*   slot  = (int*)(ws + 42076160);
  float* gpart = (float*)(ws + 42108928);

  transw_kernel<<<2048, 256, 0, stream>>>(ew, wT);
  gate_kernel<<<1024, 256, 0, stream>>>(x, wg, xbf, grec, gpart);
  scan_kernel<<<1, 1024, 0, stream>>>(grec, trec, slot, gpart, zrow, out);
  expert_gemm<<<512, 256, 0, stream>>>(xbf, wT, slot, zrow, eb, eoutb);
  combine_kernel<<<4096, 256, 0, stream>>>(eoutb, trec, out);
}